// Round 4
// baseline (243.272 us; speedup 1.0000x reference)
//
#include <hip/hip_runtime.h>
#include <hip/hip_bf16.h>

// Problem constants
#define SEQ   2048
#define BATCH 4
#define DM    768
#define NH    12
#define HD    64
#define MTOT  (BATCH*SEQ)   // 8192

typedef short bf16x8 __attribute__((ext_vector_type(8)));   // 8 bf16 = 4 VGPRs
typedef float f32x4  __attribute__((ext_vector_type(4)));

static __device__ __forceinline__ short f2bf(float f) {
  union { __hip_bfloat16 h; short s; } u;
  u.h = __float2bfloat16(f);
  return u.s;
}

// async global->LDS, 16 B per lane (global_load_lds_dwordx4)
static __device__ __forceinline__ void async_cp16(const short* g, short* l) {
  __builtin_amdgcn_global_load_lds(
      (const __attribute__((address_space(1))) void*)g,
      (__attribute__((address_space(3))) void*)l, 16, 0, 0);
}

// ------------------------------------------- fused fp32 -> bf16 (x + 4 weights)
__global__ void cvt5_kernel(const float* __restrict__ x, const float* __restrict__ wq,
                            const float* __restrict__ wk, const float* __restrict__ wv,
                            const float* __restrict__ wo, short* __restrict__ dst) {
  const int NX4 = MTOT * DM / 4, NW4 = DM * DM / 4, TOT4 = NX4 + 4 * NW4;
  int i = blockIdx.x * blockDim.x + threadIdx.x;
  if (i >= TOT4) return;
  const float* src; int off;
  if (i < NX4) { src = x; off = i; }
  else {
    int j = i - NX4; int sel = j / NW4; off = j - sel * NW4;
    src = (sel == 0) ? wq : (sel == 1) ? wk : (sel == 2) ? wv : wo;
  }
  float4 v = reinterpret_cast<const float4*>(src)[off];
  short4 o;
  o.x = f2bf(v.x); o.y = f2bf(v.y); o.z = f2bf(v.z); o.w = f2bf(v.w);
  reinterpret_cast<short4*>(dst)[i] = o;
}

// ---------------------------------------------- m97-style 128x128 LDS-staged GEMM core
// (round-0 verified structure; only addition is s_setprio around the MFMA cluster)
static __device__ __forceinline__ void gemm_lds_core(
    const short* __restrict__ A, const short* __restrict__ W,
    short* As, short* Bs, int m0, int n0, f32x4 acc[4][4])
{
  const int t = threadIdx.x;
  const int lane = t & 63, w = t >> 6;
  const int quad = lane >> 4, lq = lane & 15;
  const int mw = (w & 1) * 64, nw = (w >> 1) * 64;
  const int r0 = t >> 2, c0 = (t & 3) * 8;
  const short* ga0 = A + (size_t)(m0 + r0) * DM + c0;
  const short* ga1 = A + (size_t)(m0 + 64 + r0) * DM + c0;
  const short* gb0 = W + (size_t)(n0 + r0) * DM + c0;
  const short* gb1 = W + (size_t)(n0 + 64 + r0) * DM + c0;
  short* la0 = As + t * 8;
  short* la1 = As + 2048 + t * 8;
  short* lb0 = Bs + t * 8;
  short* lb1 = Bs + 2048 + t * 8;

  for (int k0 = 0; k0 < DM; k0 += 32) {
    async_cp16(ga0 + k0, la0);
    async_cp16(ga1 + k0, la1);
    async_cp16(gb0 + k0, lb0);
    async_cp16(gb1 + k0, lb1);
    __syncthreads();
    bf16x8 af[4], bf[4];
#pragma unroll
    for (int i = 0; i < 4; ++i) {
      af[i] = *(const bf16x8*)(As + (mw + i * 16 + lq) * 32 + quad * 8);
      bf[i] = *(const bf16x8*)(Bs + (nw + i * 16 + lq) * 32 + quad * 8);
    }
    __builtin_amdgcn_s_setprio(1);
#pragma unroll
    for (int mt = 0; mt < 4; ++mt)
#pragma unroll
      for (int nt = 0; nt < 4; ++nt)
        acc[mt][nt] = __builtin_amdgcn_mfma_f32_16x16x32_bf16(af[mt], bf[nt], acc[mt][nt], 0, 0, 0);
    __builtin_amdgcn_s_setprio(0);
    __syncthreads();
  }
}

// --------------------------------------------------------------- fused QKV projection
__global__ __launch_bounds__(256) void qkv_gemm(
    const short* __restrict__ xb, const short* __restrict__ Wall,
    short* __restrict__ Qb, short* __restrict__ Kb, short* __restrict__ VTb)
{
  __shared__ __align__(16) short As[4096], Bs[4096];
  const int m0 = blockIdx.y * 128, n0 = blockIdx.x * 128;
  f32x4 acc[4][4] = {};
  gemm_lds_core(xb, Wall, As, Bs, m0, n0, acc);

  const int t = threadIdx.x;
  const int lane = t & 63, w = t >> 6;
  const int quad = lane >> 4, lq = lane & 15;
  const int mwb = m0 + (w & 1) * 64, nwb = n0 + (w >> 1) * 64;
#pragma unroll
  for (int mt = 0; mt < 4; ++mt)
#pragma unroll
    for (int nt = 0; nt < 4; ++nt) {
      const int n = nwb + nt * 16 + lq;
      const int z = n / DM, nn = n % DM;
      const int h = nn >> 6, d = nn & 63;
      const int mbase = mwb + mt * 16 + quad * 4;
      const int b = mbase >> 11, s0 = mbase & 2047;
      if (z == 2) {
        short4 v;
        v.x = f2bf(acc[mt][nt][0]); v.y = f2bf(acc[mt][nt][1]);
        v.z = f2bf(acc[mt][nt][2]); v.w = f2bf(acc[mt][nt][3]);
        *(short4*)(VTb + ((size_t)(b * NH + h) * HD + d) * SEQ + s0) = v;
      } else {
        short* dst = (z == 0) ? Qb : Kb;
#pragma unroll
        for (int r = 0; r < 4; ++r)
          dst[((size_t)(b * NH + h) * SEQ + s0 + r) * HD + d] = f2bf(acc[mt][nt][r]);
      }
    }
}

// ------------------------------------------------------------ flash attention
// Round-0 verified structure (single-buffer K/V staging, two __syncthreads per
// tile, unconditional-per-tile softmax semantics). Exactly two compute-local
// additions, no sync/memory changes:
//   (1) wave-uniform causal fast path: q0b/q1b are wave-uniform, so tiles with
//       kb+31 <= qb are fully unmasked -> skip the 8x{cmp,cndmask}. Masking is
//       the identity there and max re-association is exact (bit-identical).
//   (2) s_setprio(1) around the MFMA clusters (HW priority hint, no semantics).
__global__ __launch_bounds__(256) void attn_kernel(
    const short* __restrict__ Qb, const short* __restrict__ Kb,
    const short* __restrict__ VTb, short* __restrict__ AOb)
{
  __shared__ __align__(16) short Ks[32 * 64];   // [keyoff][hd], chunk-swizzled
  __shared__ __align__(16) short Vs[64 * 32];   // [hd][keyoff]
  const int bp = blockIdx.x;
  const int bh = bp % 48;
  const int g  = bp / 48;              // 0..15
  const int tid = threadIdx.x;
  const int w = tid >> 6, lane = tid & 63;
  const int quad = lane >> 4, lq = lane & 15;
  const int tp = 4 * g + w;            // pair id 0..63
  const int b = bh / NH, h = bh % NH;
  const int q0b = 16 * tp;             // qt0 query base
  const int q1b = 2032 - 16 * tp;      // qt1 query base
  const int E0 = q0b + 16;             // qt0 key range end
  const int E1 = q1b + 16;             // qt1 key range end
  const int Eblk = 2048 - 64 * g;      // block-uniform loop bound (= E1 of w=0)

  const short* Qh = Qb  + (size_t)bh * SEQ * HD;
  const short* Kh = Kb  + (size_t)bh * SEQ * HD;
  const short* Vh = VTb + (size_t)bh * HD * SEQ;

  // Q fragments (B-operand): lane holds Q[qb+lq][hh*32+quad*8+j]
  bf16x8 qf0[2], qf1[2];
#pragma unroll
  for (int hh = 0; hh < 2; ++hh) {
    qf0[hh] = *(const bf16x8*)(Qh + (size_t)(q0b + lq) * HD + hh * 32 + quad * 8);
    qf1[hh] = *(const bf16x8*)(Qh + (size_t)(q1b + lq) * HD + hh * 32 + quad * 8);
  }

  f32x4 o0[4] = {}, o1[4] = {};        // O^T[hd=mt*16+quad*4+r][q=qb+lq]
  float m0v = -3e38f, m1v = -3e38f;
  float l0v = 0.0f, l1v = 0.0f;        // full per-lane l (round-0 semantics)
  const float Cc = 0.18033688011112042f;  // log2(e)/sqrt(64)

  // ---- K staging, source-swizzled: LDS slot s of row r holds global chunk
  // s^swz(r); LDS dest stays linear (tid*16B, per global_load_lds rule).
  const int srow = tid >> 3, sslot = tid & 7;
  const int sswz = (srow & 3) | (((srow >> 3) & 1) << 2);
  const short* gK = Kh + (size_t)srow * HD + (sslot ^ sswz) * 8;
  const short* gV = Vh + (size_t)(tid >> 2) * SEQ + (tid & 3) * 8;
  short* lK = Ks + tid * 8;
  short* lV = Vs + tid * 8;

  // reader-side swizzle: rows 8*(lq>>2)+4*t2+(lq&3) all have
  // swz(row) = (lq&3)|(((lq>>2)&1)<<2)
  const int rswz = (lq & 3) | (((lq >> 2) & 1) << 2);

  for (int kb = 0; kb < Eblk; kb += 32) {
    async_cp16(gK + (size_t)kb * HD, lK);
    async_cp16(gV + kb, lV);
    __syncthreads();
    if (kb < E1) {
      const bool act0 = kb < E0;
      // ---- S^T = K.Q^T (K rows permuted so P exits in PV B-operand layout)
      f32x4 st0[2] = {}, st1[2] = {};
      __builtin_amdgcn_s_setprio(1);
#pragma unroll
      for (int t2 = 0; t2 < 2; ++t2) {
        const int row = 8 * (lq >> 2) + 4 * t2 + (lq & 3);
        const int sl0 = quad ^ rswz;
        bf16x8 k0 = *(const bf16x8*)(Ks + row * 64 + sl0 * 8);
        bf16x8 k1 = *(const bf16x8*)(Ks + row * 64 + (sl0 ^ 4) * 8);
        st1[t2] = __builtin_amdgcn_mfma_f32_16x16x32_bf16(k0, qf1[0], st1[t2], 0, 0, 0);
        st1[t2] = __builtin_amdgcn_mfma_f32_16x16x32_bf16(k1, qf1[1], st1[t2], 0, 0, 0);
        if (act0) {
          st0[t2] = __builtin_amdgcn_mfma_f32_16x16x32_bf16(k0, qf0[0], st0[t2], 0, 0, 0);
          st0[t2] = __builtin_amdgcn_mfma_f32_16x16x32_bf16(k1, qf0[1], st0[t2], 0, 0, 0);
        }
      }
      __builtin_amdgcn_s_setprio(0);
      // ---- V fragments (A-operand: rows = hd, k = key offset; conflict-free)
      bf16x8 vf[4];
#pragma unroll
      for (int mt = 0; mt < 4; ++mt)
        vf[mt] = *(const bf16x8*)(Vs + (mt * 16 + lq) * 32 + quad * 8);

      // ================= qt1 softmax (round-0 math; fast path exact) ==========
      bf16x8 pf1;
      {
        float mx;
        if (kb + 31 <= q1b) {
          // fully-unmasked tile (wave-uniform): masking is the identity here;
          // max re-association is exact.
          mx = fmaxf(fmaxf(fmaxf(st1[0][0], st1[0][1]), fmaxf(st1[0][2], st1[0][3])),
                     fmaxf(fmaxf(st1[1][0], st1[1][1]), fmaxf(st1[1][2], st1[1][3])));
        } else {
          const int qv = q1b + lq;
          mx = -3e38f;
#pragma unroll
          for (int t2 = 0; t2 < 2; ++t2)
#pragma unroll
            for (int r = 0; r < 4; ++r) {
              const int key = kb + 8 * quad + 4 * t2 + r;
              const float v = (key <= qv) ? st1[t2][r] : -3e38f;
              st1[t2][r] = v;
              mx = fmaxf(mx, v);
            }
        }
        mx = fmaxf(mx, __shfl_xor(mx, 16));
        mx = fmaxf(mx, __shfl_xor(mx, 32));
        const float mn = fmaxf(m1v, mx);
        const float al = __builtin_amdgcn_exp2f((m1v - mn) * Cc);
        m1v = mn;
        float rs = 0.0f;
#pragma unroll
        for (int t2 = 0; t2 < 2; ++t2)
#pragma unroll
          for (int r = 0; r < 4; ++r) {
            const float p = __builtin_amdgcn_exp2f((st1[t2][r] - mn) * Cc);
            rs += p;
            pf1[t2 * 4 + r] = f2bf(p);
          }
        rs += __shfl_xor(rs, 16);
        rs += __shfl_xor(rs, 32);
        if (!__all(al == 1.0f)) {      // exact identity skip (mul by 1.0)
          l1v *= al;
#pragma unroll
          for (int mt = 0; mt < 4; ++mt)
#pragma unroll
            for (int r = 0; r < 4; ++r)
              o1[mt][r] *= al;
        }
        l1v += rs;
      }
      // ================= qt0 softmax (round-0 math; fast path exact) ==========
      bf16x8 pf0;
      if (act0) {
        float mx;
        if (kb + 31 <= q0b) {
          mx = fmaxf(fmaxf(fmaxf(st0[0][0], st0[0][1]), fmaxf(st0[0][2], st0[0][3])),
                     fmaxf(fmaxf(st0[1][0], st0[1][1]), fmaxf(st0[1][2], st0[1][3])));
        } else {
          const int qv = q0b + lq;
          mx = -3e38f;
#pragma unroll
          for (int t2 = 0; t2 < 2; ++t2)
#pragma unroll
            for (int r = 0; r < 4; ++r) {
              const int key = kb + 8 * quad + 4 * t2 + r;
              const float v = (key <= qv) ? st0[t2][r] : -3e38f;
              st0[t2][r] = v;
              mx = fmaxf(mx, v);
            }
        }
        mx = fmaxf(mx, __shfl_xor(mx, 16));
        mx = fmaxf(mx, __shfl_xor(mx, 32));
        const float mn = fmaxf(m0v, mx);
        const float al = __builtin_amdgcn_exp2f((m0v - mn) * Cc);
        m0v = mn;
        float rs = 0.0f;
#pragma unroll
        for (int t2 = 0; t2 < 2; ++t2)
#pragma unroll
          for (int r = 0; r < 4; ++r) {
            const float p = __builtin_amdgcn_exp2f((st0[t2][r] - mn) * Cc);
            rs += p;
            pf0[t2 * 4 + r] = f2bf(p);
          }
        rs += __shfl_xor(rs, 16);
        rs += __shfl_xor(rs, 32);
        if (!__all(al == 1.0f)) {      // exact identity skip (mul by 1.0)
          l0v *= al;
#pragma unroll
          for (int mt = 0; mt < 4; ++mt)
#pragma unroll
            for (int r = 0; r < 4; ++r)
              o0[mt][r] *= al;
        }
        l0v += rs;
      }
      // ---- O^T += V^T . P^T
      __builtin_amdgcn_s_setprio(1);
#pragma unroll
      for (int mt = 0; mt < 4; ++mt) {
        o1[mt] = __builtin_amdgcn_mfma_f32_16x16x32_bf16(vf[mt], pf1, o1[mt], 0, 0, 0);
        if (act0)
          o0[mt] = __builtin_amdgcn_mfma_f32_16x16x32_bf16(vf[mt], pf0, o0[mt], 0, 0, 0);
      }
      __builtin_amdgcn_s_setprio(0);
    }
    __syncthreads();
  }

  // ---- epilogue: normalize, store (l already full per lane)
  {
    const float inv = 1.0f / l1v;
    const int q = q1b + lq;
#pragma unroll
    for (int mt = 0; mt < 4; ++mt) {
      short4 v;
      v.x = f2bf(o1[mt][0] * inv);
      v.y = f2bf(o1[mt][1] * inv);
      v.z = f2bf(o1[mt][2] * inv);
      v.w = f2bf(o1[mt][3] * inv);
      *(short4*)(AOb + ((size_t)(b * SEQ + q)) * DM + h * HD + mt * 16 + quad * 4) = v;
    }
  }
  {
    const float inv = 1.0f / l0v;
    const int q = q0b + lq;
#pragma unroll
    for (int mt = 0; mt < 4; ++mt) {
      short4 v;
      v.x = f2bf(o0[mt][0] * inv);
      v.y = f2bf(o0[mt][1] * inv);
      v.z = f2bf(o0[mt][2] * inv);
      v.w = f2bf(o0[mt][3] * inv);
      *(short4*)(AOb + ((size_t)(b * SEQ + q)) * DM + h * HD + mt * 16 + quad * 4) = v;
    }
  }
}

// ----------------------------------------------------------- output projection
__global__ __launch_bounds__(256) void out_gemm(
    const short* __restrict__ AOb, const short* __restrict__ Wob, float* __restrict__ C)
{
  __shared__ __align__(16) short As[4096], Bs[4096];
  const int m0 = blockIdx.y * 128, n0 = blockIdx.x * 128;
  f32x4 acc[4][4] = {};
  gemm_lds_core(AOb, Wob, As, Bs, m0, n0, acc);

  const int t = threadIdx.x;
  const int lane = t & 63, w = t >> 6;
  const int quad = lane >> 4, lq = lane & 15;
  const int mwb = m0 + (w & 1) * 64, nwb = n0 + (w >> 1) * 64;
#pragma unroll
  for (int mt = 0; mt < 4; ++mt)
#pragma unroll
    for (int nt = 0; nt < 4; ++nt) {
      const int n = nwb + nt * 16 + lq;
      const int mbase = mwb + mt * 16 + quad * 4;
#pragma unroll
      for (int r = 0; r < 4; ++r)
        C[(size_t)(mbase + r) * DM + n] = acc[mt][nt][r];
    }
}

// ------------------------------------------------------------------- launcher
extern "C" void kernel_launch(void* const* d_in, const int* in_sizes, int n_in,
                              void* d_out, int out_size, void* d_ws, size_t ws_size,
                              hipStream_t stream) {
  const float* x  = (const float*)d_in[0];
  const float* Wq = (const float*)d_in[1];
  const float* Wk = (const float*)d_in[2];
  const float* Wv = (const float*)d_in[3];
  const float* Wo = (const float*)d_in[4];
  float* out = (float*)d_out;

  short* xb  = (short*)d_ws;                       // 8192*768
  short* Wqb = xb  + (size_t)MTOT * DM;
  short* Wkb = Wqb + DM * DM;
  short* Wvb = Wkb + DM * DM;
  short* Wob = Wvb + DM * DM;
  short* Qb  = Wob + DM * DM;                      // (b,h,s,d)
  short* Kb  = Qb  + (size_t)MTOT * DM;            // (b,h,s,d)
  short* VTb = Kb  + (size_t)MTOT * DM;            // (b,h,d,s)
  short* AOb = xb;                                 // alias: xb dead after qkv_gemm

  const int TOT4 = (MTOT * DM + 4 * DM * DM) / 4;
  cvt5_kernel<<<(TOT4 + 255) / 256, 256, 0, stream>>>(x, Wq, Wk, Wv, Wo, xb);

  qkv_gemm<<<dim3(3 * DM / 128, MTOT / 128), 256, 0, stream>>>(xb, Wqb, Qb, Kb, VTb);
  attn_kernel<<<dim3(768), 256, 0, stream>>>(Qb, Kb, VTb, AOb);
  out_gemm<<<dim3(DM / 128, MTOT / 128), 256, 0, stream>>>(AOb, Wob, out);
}

// Round 6
// 228.253 us; speedup vs baseline: 1.0658x; 1.0658x over previous
//
#include <hip/hip_runtime.h>
#include <hip/hip_bf16.h>

// Problem constants
#define SEQ   2048
#define BATCH 4
#define DM    768
#define NH    12
#define HD    64
#define MTOT  (BATCH*SEQ)   // 8192

typedef short bf16x8 __attribute__((ext_vector_type(8)));   // 8 bf16 = 4 VGPRs
typedef float f32x4  __attribute__((ext_vector_type(4)));

static __device__ __forceinline__ short f2bf(float f) {
  union { __hip_bfloat16 h; short s; } u;
  u.h = __float2bfloat16(f);
  return u.s;
}

// async global->LDS, 16 B per lane (global_load_lds_dwordx4)
static __device__ __forceinline__ void async_cp16(const short* g, short* l) {
  __builtin_amdgcn_global_load_lds(
      (const __attribute__((address_space(1))) void*)g,
      (__attribute__((address_space(3))) void*)l, 16, 0, 0);
}

// ------------------------------------------- fused fp32 -> bf16 (x + 4 weights)
__global__ void cvt5_kernel(const float* __restrict__ x, const float* __restrict__ wq,
                            const float* __restrict__ wk, const float* __restrict__ wv,
                            const float* __restrict__ wo, short* __restrict__ dst) {
  const int NX4 = MTOT * DM / 4, NW4 = DM * DM / 4, TOT4 = NX4 + 4 * NW4;
  int i = blockIdx.x * blockDim.x + threadIdx.x;
  if (i >= TOT4) return;
  const float* src; int off;
  if (i < NX4) { src = x; off = i; }
  else {
    int j = i - NX4; int sel = j / NW4; off = j - sel * NW4;
    src = (sel == 0) ? wq : (sel == 1) ? wk : (sel == 2) ? wv : wo;
  }
  float4 v = reinterpret_cast<const float4*>(src)[off];
  short4 o;
  o.x = f2bf(v.x); o.y = f2bf(v.y); o.z = f2bf(v.z); o.w = f2bf(v.w);
  reinterpret_cast<short4*>(dst)[i] = o;
}

// ---------------------------------------------- m97-style 128x128 LDS-staged GEMM core
// Round-0 verified structure VERBATIM (no setprio: m190/R4 showed setprio is a
// regression on barrier-synced lockstep GEMM).
static __device__ __forceinline__ void gemm_lds_core(
    const short* __restrict__ A, const short* __restrict__ W,
    short* As, short* Bs, int m0, int n0, f32x4 acc[4][4])
{
  const int t = threadIdx.x;
  const int lane = t & 63, w = t >> 6;
  const int quad = lane >> 4, lq = lane & 15;
  const int mw = (w & 1) * 64, nw = (w >> 1) * 64;
  const int r0 = t >> 2, c0 = (t & 3) * 8;
  const short* ga0 = A + (size_t)(m0 + r0) * DM + c0;
  const short* ga1 = A + (size_t)(m0 + 64 + r0) * DM + c0;
  const short* gb0 = W + (size_t)(n0 + r0) * DM + c0;
  const short* gb1 = W + (size_t)(n0 + 64 + r0) * DM + c0;
  short* la0 = As + t * 8;
  short* la1 = As + 2048 + t * 8;
  short* lb0 = Bs + t * 8;
  short* lb1 = Bs + 2048 + t * 8;

  for (int k0 = 0; k0 < DM; k0 += 32) {
    async_cp16(ga0 + k0, la0);
    async_cp16(ga1 + k0, la1);
    async_cp16(gb0 + k0, lb0);
    async_cp16(gb1 + k0, lb1);
    __syncthreads();
    bf16x8 af[4], bf[4];
#pragma unroll
    for (int i = 0; i < 4; ++i) {
      af[i] = *(const bf16x8*)(As + (mw + i * 16 + lq) * 32 + quad * 8);
      bf[i] = *(const bf16x8*)(Bs + (nw + i * 16 + lq) * 32 + quad * 8);
    }
#pragma unroll
    for (int mt = 0; mt < 4; ++mt)
#pragma unroll
      for (int nt = 0; nt < 4; ++nt)
        acc[mt][nt] = __builtin_amdgcn_mfma_f32_16x16x32_bf16(af[mt], bf[nt], acc[mt][nt], 0, 0, 0);
    __syncthreads();
  }
}

// XCD-aware bijective block swizzle (T1): grid size must be divisible by 8.
// Blocks with the same (bid % 8) dispatch to the same XCD; give each XCD a
// contiguous chunk of the tile space for L2 locality. Pure index remap, the
// computed results are bit-identical.
static __device__ __forceinline__ int xcd_swz(int wg, int nwg) {
  return (wg & 7) * (nwg >> 3) + (wg >> 3);
}

// --------------------------------------------------------------- fused QKV projection
__global__ __launch_bounds__(256) void qkv_gemm(
    const short* __restrict__ xb, const short* __restrict__ Wall,
    short* __restrict__ Qb, short* __restrict__ Kb, short* __restrict__ VTb)
{
  __shared__ __align__(16) short As[4096], Bs[4096];
  // grid = 18 x 64 = 1152 blocks (divisible by 8) -> bijective swizzle
  const int nwg = gridDim.x * gridDim.y;
  const int wg = xcd_swz(blockIdx.y * gridDim.x + blockIdx.x, nwg);
  const int m0 = (wg / gridDim.x) * 128, n0 = (wg % gridDim.x) * 128;
  f32x4 acc[4][4] = {};
  gemm_lds_core(xb, Wall, As, Bs, m0, n0, acc);

  const int t = threadIdx.x;
  const int lane = t & 63, w = t >> 6;
  const int quad = lane >> 4, lq = lane & 15;
  const int mwb = m0 + (w & 1) * 64, nwb = n0 + (w >> 1) * 64;
#pragma unroll
  for (int mt = 0; mt < 4; ++mt)
#pragma unroll
    for (int nt = 0; nt < 4; ++nt) {
      const int n = nwb + nt * 16 + lq;
      const int z = n / DM, nn = n % DM;
      const int h = nn >> 6, d = nn & 63;
      const int mbase = mwb + mt * 16 + quad * 4;
      const int b = mbase >> 11, s0 = mbase & 2047;
      if (z == 2) {
        short4 v;
        v.x = f2bf(acc[mt][nt][0]); v.y = f2bf(acc[mt][nt][1]);
        v.z = f2bf(acc[mt][nt][2]); v.w = f2bf(acc[mt][nt][3]);
        *(short4*)(VTb + ((size_t)(b * NH + h) * HD + d) * SEQ + s0) = v;
      } else {
        short* dst = (z == 0) ? Qb : Kb;
#pragma unroll
        for (int r = 0; r < 4; ++r)
          dst[((size_t)(b * NH + h) * SEQ + s0 + r) * HD + d] = f2bf(acc[mt][nt][r]);
      }
    }
}

// ------------------------------------------------------------ flash attention
// Round-4 verified kernel VERBATIM (passed, 87.6us, absmax 0.015625):
// single-buffer K/V staging, two __syncthreads per 32-key tile, causal
// fast path + setprio. Block->XCD mapping is already optimal: all 16 g-blocks
// sharing one (b,h)'s KV satisfy (g*48+bh)%8 == bh%8 -> same XCD.
__global__ __launch_bounds__(256) void attn_kernel(
    const short* __restrict__ Qb, const short* __restrict__ Kb,
    const short* __restrict__ VTb, short* __restrict__ AOb)
{
  __shared__ __align__(16) short Ks[32 * 64];   // [keyoff][hd], chunk-swizzled
  __shared__ __align__(16) short Vs[64 * 32];   // [hd][keyoff]
  const int bp = blockIdx.x;
  const int bh = bp % 48;
  const int g  = bp / 48;              // 0..15
  const int tid = threadIdx.x;
  const int w = tid >> 6, lane = tid & 63;
  const int quad = lane >> 4, lq = lane & 15;
  const int tp = 4 * g + w;            // pair id 0..63
  const int b = bh / NH, h = bh % NH;
  const int q0b = 16 * tp;             // qt0 query base
  const int q1b = 2032 - 16 * tp;      // qt1 query base
  const int E0 = q0b + 16;             // qt0 key range end
  const int E1 = q1b + 16;             // qt1 key range end
  const int Eblk = 2048 - 64 * g;      // block-uniform loop bound (= E1 of w=0)

  const short* Qh = Qb  + (size_t)bh * SEQ * HD;
  const short* Kh = Kb  + (size_t)bh * SEQ * HD;
  const short* Vh = VTb + (size_t)bh * HD * SEQ;

  // Q fragments (B-operand): lane holds Q[qb+lq][hh*32+quad*8+j]
  bf16x8 qf0[2], qf1[2];
#pragma unroll
  for (int hh = 0; hh < 2; ++hh) {
    qf0[hh] = *(const bf16x8*)(Qh + (size_t)(q0b + lq) * HD + hh * 32 + quad * 8);
    qf1[hh] = *(const bf16x8*)(Qh + (size_t)(q1b + lq) * HD + hh * 32 + quad * 8);
  }

  f32x4 o0[4] = {}, o1[4] = {};        // O^T[hd=mt*16+quad*4+r][q=qb+lq]
  float m0v = -3e38f, m1v = -3e38f;
  float l0v = 0.0f, l1v = 0.0f;        // full per-lane l (round-0 semantics)
  const float Cc = 0.18033688011112042f;  // log2(e)/sqrt(64)

  // ---- K staging, source-swizzled: LDS slot s of row r holds global chunk
  // s^swz(r); LDS dest stays linear (tid*16B, per global_load_lds rule).
  const int srow = tid >> 3, sslot = tid & 7;
  const int sswz = (srow & 3) | (((srow >> 3) & 1) << 2);
  const short* gK = Kh + (size_t)srow * HD + (sslot ^ sswz) * 8;
  const short* gV = Vh + (size_t)(tid >> 2) * SEQ + (tid & 3) * 8;
  short* lK = Ks + tid * 8;
  short* lV = Vs + tid * 8;

  // reader-side swizzle: rows 8*(lq>>2)+4*t2+(lq&3) all have
  // swz(row) = (lq&3)|(((lq>>2)&1)<<2)
  const int rswz = (lq & 3) | (((lq >> 2) & 1) << 2);

  for (int kb = 0; kb < Eblk; kb += 32) {
    async_cp16(gK + (size_t)kb * HD, lK);
    async_cp16(gV + kb, lV);
    __syncthreads();
    if (kb < E1) {
      const bool act0 = kb < E0;
      // ---- S^T = K.Q^T (K rows permuted so P exits in PV B-operand layout)
      f32x4 st0[2] = {}, st1[2] = {};
      __builtin_amdgcn_s_setprio(1);
#pragma unroll
      for (int t2 = 0; t2 < 2; ++t2) {
        const int row = 8 * (lq >> 2) + 4 * t2 + (lq & 3);
        const int sl0 = quad ^ rswz;
        bf16x8 k0 = *(const bf16x8*)(Ks + row * 64 + sl0 * 8);
        bf16x8 k1 = *(const bf16x8*)(Ks + row * 64 + (sl0 ^ 4) * 8);
        st1[t2] = __builtin_amdgcn_mfma_f32_16x16x32_bf16(k0, qf1[0], st1[t2], 0, 0, 0);
        st1[t2] = __builtin_amdgcn_mfma_f32_16x16x32_bf16(k1, qf1[1], st1[t2], 0, 0, 0);
        if (act0) {
          st0[t2] = __builtin_amdgcn_mfma_f32_16x16x32_bf16(k0, qf0[0], st0[t2], 0, 0, 0);
          st0[t2] = __builtin_amdgcn_mfma_f32_16x16x32_bf16(k1, qf0[1], st0[t2], 0, 0, 0);
        }
      }
      __builtin_amdgcn_s_setprio(0);
      // ---- V fragments (A-operand: rows = hd, k = key offset; conflict-free)
      bf16x8 vf[4];
#pragma unroll
      for (int mt = 0; mt < 4; ++mt)
        vf[mt] = *(const bf16x8*)(Vs + (mt * 16 + lq) * 32 + quad * 8);

      // ================= qt1 softmax (round-0 math; fast path exact) ==========
      bf16x8 pf1;
      {
        float mx;
        if (kb + 31 <= q1b) {
          // fully-unmasked tile (wave-uniform): masking is the identity here;
          // max re-association is exact.
          mx = fmaxf(fmaxf(fmaxf(st1[0][0], st1[0][1]), fmaxf(st1[0][2], st1[0][3])),
                     fmaxf(fmaxf(st1[1][0], st1[1][1]), fmaxf(st1[1][2], st1[1][3])));
        } else {
          const int qv = q1b + lq;
          mx = -3e38f;
#pragma unroll
          for (int t2 = 0; t2 < 2; ++t2)
#pragma unroll
            for (int r = 0; r < 4; ++r) {
              const int key = kb + 8 * quad + 4 * t2 + r;
              const float v = (key <= qv) ? st1[t2][r] : -3e38f;
              st1[t2][r] = v;
              mx = fmaxf(mx, v);
            }
        }
        mx = fmaxf(mx, __shfl_xor(mx, 16));
        mx = fmaxf(mx, __shfl_xor(mx, 32));
        const float mn = fmaxf(m1v, mx);
        const float al = __builtin_amdgcn_exp2f((m1v - mn) * Cc);
        m1v = mn;
        float rs = 0.0f;
#pragma unroll
        for (int t2 = 0; t2 < 2; ++t2)
#pragma unroll
          for (int r = 0; r < 4; ++r) {
            const float p = __builtin_amdgcn_exp2f((st1[t2][r] - mn) * Cc);
            rs += p;
            pf1[t2 * 4 + r] = f2bf(p);
          }
        rs += __shfl_xor(rs, 16);
        rs += __shfl_xor(rs, 32);
        if (!__all(al == 1.0f)) {      // exact identity skip (mul by 1.0)
          l1v *= al;
#pragma unroll
          for (int mt = 0; mt < 4; ++mt)
#pragma unroll
            for (int r = 0; r < 4; ++r)
              o1[mt][r] *= al;
        }
        l1v += rs;
      }
      // ================= qt0 softmax (round-0 math; fast path exact) ==========
      bf16x8 pf0;
      if (act0) {
        float mx;
        if (kb + 31 <= q0b) {
          mx = fmaxf(fmaxf(fmaxf(st0[0][0], st0[0][1]), fmaxf(st0[0][2], st0[0][3])),
                     fmaxf(fmaxf(st0[1][0], st0[1][1]), fmaxf(st0[1][2], st0[1][3])));
        } else {
          const int qv = q0b + lq;
          mx = -3e38f;
#pragma unroll
          for (int t2 = 0; t2 < 2; ++t2)
#pragma unroll
            for (int r = 0; r < 4; ++r) {
              const int key = kb + 8 * quad + 4 * t2 + r;
              const float v = (key <= qv) ? st0[t2][r] : -3e38f;
              st0[t2][r] = v;
              mx = fmaxf(mx, v);
            }
        }
        mx = fmaxf(mx, __shfl_xor(mx, 16));
        mx = fmaxf(mx, __shfl_xor(mx, 32));
        const float mn = fmaxf(m0v, mx);
        const float al = __builtin_amdgcn_exp2f((m0v - mn) * Cc);
        m0v = mn;
        float rs = 0.0f;
#pragma unroll
        for (int t2 = 0; t2 < 2; ++t2)
#pragma unroll
          for (int r = 0; r < 4; ++r) {
            const float p = __builtin_amdgcn_exp2f((st0[t2][r] - mn) * Cc);
            rs += p;
            pf0[t2 * 4 + r] = f2bf(p);
          }
        rs += __shfl_xor(rs, 16);
        rs += __shfl_xor(rs, 32);
        if (!__all(al == 1.0f)) {      // exact identity skip (mul by 1.0)
          l0v *= al;
#pragma unroll
          for (int mt = 0; mt < 4; ++mt)
#pragma unroll
            for (int r = 0; r < 4; ++r)
              o0[mt][r] *= al;
        }
        l0v += rs;
      }
      // ---- O^T += V^T . P^T
      __builtin_amdgcn_s_setprio(1);
#pragma unroll
      for (int mt = 0; mt < 4; ++mt) {
        o1[mt] = __builtin_amdgcn_mfma_f32_16x16x32_bf16(vf[mt], pf1, o1[mt], 0, 0, 0);
        if (act0)
          o0[mt] = __builtin_amdgcn_mfma_f32_16x16x32_bf16(vf[mt], pf0, o0[mt], 0, 0, 0);
      }
      __builtin_amdgcn_s_setprio(0);
    }
    __syncthreads();
  }

  // ---- epilogue: normalize, store (l already full per lane)
  {
    const float inv = 1.0f / l1v;
    const int q = q1b + lq;
#pragma unroll
    for (int mt = 0; mt < 4; ++mt) {
      short4 v;
      v.x = f2bf(o1[mt][0] * inv);
      v.y = f2bf(o1[mt][1] * inv);
      v.z = f2bf(o1[mt][2] * inv);
      v.w = f2bf(o1[mt][3] * inv);
      *(short4*)(AOb + ((size_t)(b * SEQ + q)) * DM + h * HD + mt * 16 + quad * 4) = v;
    }
  }
  {
    const float inv = 1.0f / l0v;
    const int q = q0b + lq;
#pragma unroll
    for (int mt = 0; mt < 4; ++mt) {
      short4 v;
      v.x = f2bf(o0[mt][0] * inv);
      v.y = f2bf(o0[mt][1] * inv);
      v.z = f2bf(o0[mt][2] * inv);
      v.w = f2bf(o0[mt][3] * inv);
      *(short4*)(AOb + ((size_t)(b * SEQ + q)) * DM + h * HD + mt * 16 + quad * 4) = v;
    }
  }
}

// ----------------------------------------------------------- output projection
__global__ __launch_bounds__(256) void out_gemm(
    const short* __restrict__ AOb, const short* __restrict__ Wob, float* __restrict__ C)
{
  __shared__ __align__(16) short As[4096], Bs[4096];
  // grid = 6 x 64 = 384 blocks (divisible by 8) -> bijective swizzle
  const int nwg = gridDim.x * gridDim.y;
  const int wg = xcd_swz(blockIdx.y * gridDim.x + blockIdx.x, nwg);
  const int m0 = (wg / gridDim.x) * 128, n0 = (wg % gridDim.x) * 128;
  f32x4 acc[4][4] = {};
  gemm_lds_core(AOb, Wob, As, Bs, m0, n0, acc);

  const int t = threadIdx.x;
  const int lane = t & 63, w = t >> 6;
  const int quad = lane >> 4, lq = lane & 15;
  const int mwb = m0 + (w & 1) * 64, nwb = n0 + (w >> 1) * 64;
#pragma unroll
  for (int mt = 0; mt < 4; ++mt)
#pragma unroll
    for (int nt = 0; nt < 4; ++nt) {
      const int n = nwb + nt * 16 + lq;
      const int mbase = mwb + mt * 16 + quad * 4;
#pragma unroll
      for (int r = 0; r < 4; ++r)
        C[(size_t)(mbase + r) * DM + n] = acc[mt][nt][r];
    }
}

// ------------------------------------------------------------------- launcher
extern "C" void kernel_launch(void* const* d_in, const int* in_sizes, int n_in,
                              void* d_out, int out_size, void* d_ws, size_t ws_size,
                              hipStream_t stream) {
  const float* x  = (const float*)d_in[0];
  const float* Wq = (const float*)d_in[1];
  const float* Wk = (const float*)d_in[2];
  const float* Wv = (const float*)d_in[3];
  const float* Wo = (const float*)d_in[4];
  float* out = (float*)d_out;

  short* xb  = (short*)d_ws;                       // 8192*768
  short* Wqb = xb  + (size_t)MTOT * DM;
  short* Wkb = Wqb + DM * DM;
  short* Wvb = Wkb + DM * DM;
  short* Wob = Wvb + DM * DM;
  short* Qb  = Wob + DM * DM;                      // (b,h,s,d)
  short* Kb  = Qb  + (size_t)MTOT * DM;            // (b,h,s,d)
  short* VTb = Kb  + (size_t)MTOT * DM;            // (b,h,d,s)
  short* AOb = xb;                                 // alias: xb dead after qkv_gemm

  const int TOT4 = (MTOT * DM + 4 * DM * DM) / 4;
  cvt5_kernel<<<(TOT4 + 255) / 256, 256, 0, stream>>>(x, Wq, Wk, Wv, Wo, xb);

  qkv_gemm<<<dim3(3 * DM / 128, MTOT / 128), 256, 0, stream>>>(xb, Wqb, Qb, Kb, VTb);
  attn_kernel<<<dim3(768), 256, 0, stream>>>(Qb, Kb, VTb, AOb);
  out_gemm<<<dim3(DM / 128, MTOT / 128), 256, 0, stream>>>(AOb, Wob, out);
}

// Round 7
// 224.248 us; speedup vs baseline: 1.0848x; 1.0179x over previous
//
#include <hip/hip_runtime.h>
#include <hip/hip_bf16.h>

// Problem constants
#define SEQ   2048
#define BATCH 4
#define DM    768
#define NH    12
#define HD    64
#define MTOT  (BATCH*SEQ)   // 8192

typedef short bf16x8 __attribute__((ext_vector_type(8)));   // 8 bf16 = 4 VGPRs
typedef float f32x4  __attribute__((ext_vector_type(4)));

static __device__ __forceinline__ short f2bf(float f) {
  union { __hip_bfloat16 h; short s; } u;
  u.h = __float2bfloat16(f);
  return u.s;
}

// async global->LDS, 16 B per lane (global_load_lds_dwordx4)
static __device__ __forceinline__ void async_cp16(const short* g, short* l) {
  __builtin_amdgcn_global_load_lds(
      (const __attribute__((address_space(1))) void*)g,
      (__attribute__((address_space(3))) void*)l, 16, 0, 0);
}

// ------------------------------------------- fused fp32 -> bf16 (x + 4 weights)
__global__ void cvt5_kernel(const float* __restrict__ x, const float* __restrict__ wq,
                            const float* __restrict__ wk, const float* __restrict__ wv,
                            const float* __restrict__ wo, short* __restrict__ dst) {
  const int NX4 = MTOT * DM / 4, NW4 = DM * DM / 4, TOT4 = NX4 + 4 * NW4;
  int i = blockIdx.x * blockDim.x + threadIdx.x;
  if (i >= TOT4) return;
  const float* src; int off;
  if (i < NX4) { src = x; off = i; }
  else {
    int j = i - NX4; int sel = j / NW4; off = j - sel * NW4;
    src = (sel == 0) ? wq : (sel == 1) ? wk : (sel == 2) ? wv : wo;
  }
  float4 v = reinterpret_cast<const float4*>(src)[off];
  short4 o;
  o.x = f2bf(v.x); o.y = f2bf(v.y); o.z = f2bf(v.z); o.w = f2bf(v.w);
  reinterpret_cast<short4*>(dst)[i] = o;
}

// ---------------------------------------------- 128x128 LDS-staged GEMM core, BK=64
// Sync shape is IDENTICAL to the verified R0/R6 structure: one stage batch ->
// one __syncthreads -> one compute region -> one __syncthreads. Only the batch
// size changed (full 128x64 A and B tiles, 8 global_load_lds, fixed dests),
// halving the barrier-pair count (24 -> 12 iterations).
// The [128][64]-short layout has 128B rows -> 16-lane same-bank reads, so the
// data chunks are XOR-swizzled on the SOURCE side (LDS slot s of row r holds
// global chunk s^(r&7); LDS dest stays linear per the global_load_lds rule),
// and the reader XORs the slot by (row&7)=lq&7. 16 lanes -> 8 slots x 4 banks
// = all 32 banks, 2-way (free). K-chunk accumulation order (0,32,64,...) is
// unchanged -> bit-identical results.
static __device__ __forceinline__ void gemm_lds_core(
    const short* __restrict__ A, const short* __restrict__ W,
    short* As, short* Bs, int m0, int n0, f32x4 acc[4][4])
{
  const int t = threadIdx.x;
  const int lane = t & 63, w = t >> 6;
  const int quad = lane >> 4, lq = lane & 15;
  const int mw = (w & 1) * 64, nw = (w >> 1) * 64;
  // staging: round j covers tile rows j*32 + (t>>3); this thread's LDS slot is
  // (t&7), which must hold global chunk (t&7)^(row&7); row&7 == r0&7 for all j.
  const int r0 = t >> 3;                  // 0..31
  const int cs = (t & 7) ^ (r0 & 7);      // source chunk for this LDS slot
  const short* ga = A + (size_t)(m0 + r0) * DM + cs * 8;
  const short* gb = W + (size_t)(n0 + r0) * DM + cs * 8;
  short* la = As + t * 8;
  short* lb = Bs + t * 8;
  const int xsw = lq & 7;                 // reader-side XOR (= row & 7)

  for (int k0 = 0; k0 < DM; k0 += 64) {
    async_cp16(ga + k0,           la);
    async_cp16(ga + k0 + 32 * DM, la + 2048);
    async_cp16(ga + k0 + 64 * DM, la + 4096);
    async_cp16(ga + k0 + 96 * DM, la + 6144);
    async_cp16(gb + k0,           lb);
    async_cp16(gb + k0 + 32 * DM, lb + 2048);
    async_cp16(gb + k0 + 64 * DM, lb + 4096);
    async_cp16(gb + k0 + 96 * DM, lb + 6144);
    __syncthreads();
#pragma unroll
    for (int hh = 0; hh < 2; ++hh) {      // K sub-chunk 0..32 then 32..64
      bf16x8 af[4], bfr[4];
      const int sl = (hh * 4 + quad) ^ xsw;
#pragma unroll
      for (int i = 0; i < 4; ++i) {
        af[i]  = *(const bf16x8*)(As + (mw + i * 16 + lq) * 64 + sl * 8);
        bfr[i] = *(const bf16x8*)(Bs + (nw + i * 16 + lq) * 64 + sl * 8);
      }
#pragma unroll
      for (int mt = 0; mt < 4; ++mt)
#pragma unroll
        for (int nt = 0; nt < 4; ++nt)
          acc[mt][nt] = __builtin_amdgcn_mfma_f32_16x16x32_bf16(af[mt], bfr[nt], acc[mt][nt], 0, 0, 0);
    }
    __syncthreads();
  }
}

// XCD-aware bijective block swizzle (T1): grid size must be divisible by 8.
static __device__ __forceinline__ int xcd_swz(int wg, int nwg) {
  return (wg & 7) * (nwg >> 3) + (wg >> 3);
}

// --------------------------------------------------------------- fused QKV projection
__global__ __launch_bounds__(256) void qkv_gemm(
    const short* __restrict__ xb, const short* __restrict__ Wall,
    short* __restrict__ Qb, short* __restrict__ Kb, short* __restrict__ VTb)
{
  __shared__ __align__(16) short As[8192], Bs[8192];
  // grid = 18 x 64 = 1152 blocks (divisible by 8) -> bijective swizzle
  const int nwg = gridDim.x * gridDim.y;
  const int wg = xcd_swz(blockIdx.y * gridDim.x + blockIdx.x, nwg);
  const int m0 = (wg / gridDim.x) * 128, n0 = (wg % gridDim.x) * 128;
  f32x4 acc[4][4] = {};
  gemm_lds_core(xb, Wall, As, Bs, m0, n0, acc);

  const int t = threadIdx.x;
  const int lane = t & 63, w = t >> 6;
  const int quad = lane >> 4, lq = lane & 15;
  const int mwb = m0 + (w & 1) * 64, nwb = n0 + (w >> 1) * 64;
#pragma unroll
  for (int mt = 0; mt < 4; ++mt)
#pragma unroll
    for (int nt = 0; nt < 4; ++nt) {
      const int n = nwb + nt * 16 + lq;
      const int z = n / DM, nn = n % DM;
      const int h = nn >> 6, d = nn & 63;
      const int mbase = mwb + mt * 16 + quad * 4;
      const int b = mbase >> 11, s0 = mbase & 2047;
      if (z == 2) {
        short4 v;
        v.x = f2bf(acc[mt][nt][0]); v.y = f2bf(acc[mt][nt][1]);
        v.z = f2bf(acc[mt][nt][2]); v.w = f2bf(acc[mt][nt][3]);
        *(short4*)(VTb + ((size_t)(b * NH + h) * HD + d) * SEQ + s0) = v;
      } else {
        short* dst = (z == 0) ? Qb : Kb;
#pragma unroll
        for (int r = 0; r < 4; ++r)
          dst[((size_t)(b * NH + h) * SEQ + s0 + r) * HD + d] = f2bf(acc[mt][nt][r]);
      }
    }
}

// ------------------------------------------------------------ flash attention
// Round-6 verified kernel VERBATIM (87.6us, absmax 0.015625).
__global__ __launch_bounds__(256) void attn_kernel(
    const short* __restrict__ Qb, const short* __restrict__ Kb,
    const short* __restrict__ VTb, short* __restrict__ AOb)
{
  __shared__ __align__(16) short Ks[32 * 64];   // [keyoff][hd], chunk-swizzled
  __shared__ __align__(16) short Vs[64 * 32];   // [hd][keyoff]
  const int bp = blockIdx.x;
  const int bh = bp % 48;
  const int g  = bp / 48;              // 0..15
  const int tid = threadIdx.x;
  const int w = tid >> 6, lane = tid & 63;
  const int quad = lane >> 4, lq = lane & 15;
  const int tp = 4 * g + w;            // pair id 0..63
  const int b = bh / NH, h = bh % NH;
  const int q0b = 16 * tp;             // qt0 query base
  const int q1b = 2032 - 16 * tp;      // qt1 query base
  const int E0 = q0b + 16;             // qt0 key range end
  const int E1 = q1b + 16;             // qt1 key range end
  const int Eblk = 2048 - 64 * g;      // block-uniform loop bound (= E1 of w=0)

  const short* Qh = Qb  + (size_t)bh * SEQ * HD;
  const short* Kh = Kb  + (size_t)bh * SEQ * HD;
  const short* Vh = VTb + (size_t)bh * HD * SEQ;

  // Q fragments (B-operand): lane holds Q[qb+lq][hh*32+quad*8+j]
  bf16x8 qf0[2], qf1[2];
#pragma unroll
  for (int hh = 0; hh < 2; ++hh) {
    qf0[hh] = *(const bf16x8*)(Qh + (size_t)(q0b + lq) * HD + hh * 32 + quad * 8);
    qf1[hh] = *(const bf16x8*)(Qh + (size_t)(q1b + lq) * HD + hh * 32 + quad * 8);
  }

  f32x4 o0[4] = {}, o1[4] = {};        // O^T[hd=mt*16+quad*4+r][q=qb+lq]
  float m0v = -3e38f, m1v = -3e38f;
  float l0v = 0.0f, l1v = 0.0f;        // full per-lane l (round-0 semantics)
  const float Cc = 0.18033688011112042f;  // log2(e)/sqrt(64)

  // ---- K staging, source-swizzled: LDS slot s of row r holds global chunk
  // s^swz(r); LDS dest stays linear (tid*16B, per global_load_lds rule).
  const int srow = tid >> 3, sslot = tid & 7;
  const int sswz = (srow & 3) | (((srow >> 3) & 1) << 2);
  const short* gK = Kh + (size_t)srow * HD + (sslot ^ sswz) * 8;
  const short* gV = Vh + (size_t)(tid >> 2) * SEQ + (tid & 3) * 8;
  short* lK = Ks + tid * 8;
  short* lV = Vs + tid * 8;

  // reader-side swizzle: rows 8*(lq>>2)+4*t2+(lq&3) all have
  // swz(row) = (lq&3)|(((lq>>2)&1)<<2)
  const int rswz = (lq & 3) | (((lq >> 2) & 1) << 2);

  for (int kb = 0; kb < Eblk; kb += 32) {
    async_cp16(gK + (size_t)kb * HD, lK);
    async_cp16(gV + kb, lV);
    __syncthreads();
    if (kb < E1) {
      const bool act0 = kb < E0;
      // ---- S^T = K.Q^T (K rows permuted so P exits in PV B-operand layout)
      f32x4 st0[2] = {}, st1[2] = {};
      __builtin_amdgcn_s_setprio(1);
#pragma unroll
      for (int t2 = 0; t2 < 2; ++t2) {
        const int row = 8 * (lq >> 2) + 4 * t2 + (lq & 3);
        const int sl0 = quad ^ rswz;
        bf16x8 k0 = *(const bf16x8*)(Ks + row * 64 + sl0 * 8);
        bf16x8 k1 = *(const bf16x8*)(Ks + row * 64 + (sl0 ^ 4) * 8);
        st1[t2] = __builtin_amdgcn_mfma_f32_16x16x32_bf16(k0, qf1[0], st1[t2], 0, 0, 0);
        st1[t2] = __builtin_amdgcn_mfma_f32_16x16x32_bf16(k1, qf1[1], st1[t2], 0, 0, 0);
        if (act0) {
          st0[t2] = __builtin_amdgcn_mfma_f32_16x16x32_bf16(k0, qf0[0], st0[t2], 0, 0, 0);
          st0[t2] = __builtin_amdgcn_mfma_f32_16x16x32_bf16(k1, qf0[1], st0[t2], 0, 0, 0);
        }
      }
      __builtin_amdgcn_s_setprio(0);
      // ---- V fragments (A-operand: rows = hd, k = key offset; conflict-free)
      bf16x8 vf[4];
#pragma unroll
      for (int mt = 0; mt < 4; ++mt)
        vf[mt] = *(const bf16x8*)(Vs + (mt * 16 + lq) * 32 + quad * 8);

      // ================= qt1 softmax (round-0 math; fast path exact) ==========
      bf16x8 pf1;
      {
        float mx;
        if (kb + 31 <= q1b) {
          // fully-unmasked tile (wave-uniform): masking is the identity here;
          // max re-association is exact.
          mx = fmaxf(fmaxf(fmaxf(st1[0][0], st1[0][1]), fmaxf(st1[0][2], st1[0][3])),
                     fmaxf(fmaxf(st1[1][0], st1[1][1]), fmaxf(st1[1][2], st1[1][3])));
        } else {
          const int qv = q1b + lq;
          mx = -3e38f;
#pragma unroll
          for (int t2 = 0; t2 < 2; ++t2)
#pragma unroll
            for (int r = 0; r < 4; ++r) {
              const int key = kb + 8 * quad + 4 * t2 + r;
              const float v = (key <= qv) ? st1[t2][r] : -3e38f;
              st1[t2][r] = v;
              mx = fmaxf(mx, v);
            }
        }
        mx = fmaxf(mx, __shfl_xor(mx, 16));
        mx = fmaxf(mx, __shfl_xor(mx, 32));
        const float mn = fmaxf(m1v, mx);
        const float al = __builtin_amdgcn_exp2f((m1v - mn) * Cc);
        m1v = mn;
        float rs = 0.0f;
#pragma unroll
        for (int t2 = 0; t2 < 2; ++t2)
#pragma unroll
          for (int r = 0; r < 4; ++r) {
            const float p = __builtin_amdgcn_exp2f((st1[t2][r] - mn) * Cc);
            rs += p;
            pf1[t2 * 4 + r] = f2bf(p);
          }
        rs += __shfl_xor(rs, 16);
        rs += __shfl_xor(rs, 32);
        if (!__all(al == 1.0f)) {      // exact identity skip (mul by 1.0)
          l1v *= al;
#pragma unroll
          for (int mt = 0; mt < 4; ++mt)
#pragma unroll
            for (int r = 0; r < 4; ++r)
              o1[mt][r] *= al;
        }
        l1v += rs;
      }
      // ================= qt0 softmax (round-0 math; fast path exact) ==========
      bf16x8 pf0;
      if (act0) {
        float mx;
        if (kb + 31 <= q0b) {
          mx = fmaxf(fmaxf(fmaxf(st0[0][0], st0[0][1]), fmaxf(st0[0][2], st0[0][3])),
                     fmaxf(fmaxf(st0[1][0], st0[1][1]), fmaxf(st0[1][2], st0[1][3])));
        } else {
          const int qv = q0b + lq;
          mx = -3e38f;
#pragma unroll
          for (int t2 = 0; t2 < 2; ++t2)
#pragma unroll
            for (int r = 0; r < 4; ++r) {
              const int key = kb + 8 * quad + 4 * t2 + r;
              const float v = (key <= qv) ? st0[t2][r] : -3e38f;
              st0[t2][r] = v;
              mx = fmaxf(mx, v);
            }
        }
        mx = fmaxf(mx, __shfl_xor(mx, 16));
        mx = fmaxf(mx, __shfl_xor(mx, 32));
        const float mn = fmaxf(m0v, mx);
        const float al = __builtin_amdgcn_exp2f((m0v - mn) * Cc);
        m0v = mn;
        float rs = 0.0f;
#pragma unroll
        for (int t2 = 0; t2 < 2; ++t2)
#pragma unroll
          for (int r = 0; r < 4; ++r) {
            const float p = __builtin_amdgcn_exp2f((st0[t2][r] - mn) * Cc);
            rs += p;
            pf0[t2 * 4 + r] = f2bf(p);
          }
        rs += __shfl_xor(rs, 16);
        rs += __shfl_xor(rs, 32);
        if (!__all(al == 1.0f)) {      // exact identity skip (mul by 1.0)
          l0v *= al;
#pragma unroll
          for (int mt = 0; mt < 4; ++mt)
#pragma unroll
            for (int r = 0; r < 4; ++r)
              o0[mt][r] *= al;
        }
        l0v += rs;
      }
      // ---- O^T += V^T . P^T
      __builtin_amdgcn_s_setprio(1);
#pragma unroll
      for (int mt = 0; mt < 4; ++mt) {
        o1[mt] = __builtin_amdgcn_mfma_f32_16x16x32_bf16(vf[mt], pf1, o1[mt], 0, 0, 0);
        if (act0)
          o0[mt] = __builtin_amdgcn_mfma_f32_16x16x32_bf16(vf[mt], pf0, o0[mt], 0, 0, 0);
      }
      __builtin_amdgcn_s_setprio(0);
    }
    __syncthreads();
  }

  // ---- epilogue: normalize, store (l already full per lane)
  {
    const float inv = 1.0f / l1v;
    const int q = q1b + lq;
#pragma unroll
    for (int mt = 0; mt < 4; ++mt) {
      short4 v;
      v.x = f2bf(o1[mt][0] * inv);
      v.y = f2bf(o1[mt][1] * inv);
      v.z = f2bf(o1[mt][2] * inv);
      v.w = f2bf(o1[mt][3] * inv);
      *(short4*)(AOb + ((size_t)(b * SEQ + q)) * DM + h * HD + mt * 16 + quad * 4) = v;
    }
  }
  {
    const float inv = 1.0f / l0v;
    const int q = q0b + lq;
#pragma unroll
    for (int mt = 0; mt < 4; ++mt) {
      short4 v;
      v.x = f2bf(o0[mt][0] * inv);
      v.y = f2bf(o0[mt][1] * inv);
      v.z = f2bf(o0[mt][2] * inv);
      v.w = f2bf(o0[mt][3] * inv);
      *(short4*)(AOb + ((size_t)(b * SEQ + q)) * DM + h * HD + mt * 16 + quad * 4) = v;
    }
  }
}

// ----------------------------------------------------------- output projection
__global__ __launch_bounds__(256) void out_gemm(
    const short* __restrict__ AOb, const short* __restrict__ Wob, float* __restrict__ C)
{
  __shared__ __align__(16) short As[8192], Bs[8192];
  // grid = 6 x 64 = 384 blocks (divisible by 8) -> bijective swizzle
  const int nwg = gridDim.x * gridDim.y;
  const int wg = xcd_swz(blockIdx.y * gridDim.x + blockIdx.x, nwg);
  const int m0 = (wg / gridDim.x) * 128, n0 = (wg % gridDim.x) * 128;
  f32x4 acc[4][4] = {};
  gemm_lds_core(AOb, Wob, As, Bs, m0, n0, acc);

  const int t = threadIdx.x;
  const int lane = t & 63, w = t >> 6;
  const int quad = lane >> 4, lq = lane & 15;
  const int mwb = m0 + (w & 1) * 64, nwb = n0 + (w >> 1) * 64;
#pragma unroll
  for (int mt = 0; mt < 4; ++mt)
#pragma unroll
    for (int nt = 0; nt < 4; ++nt) {
      const int n = nwb + nt * 16 + lq;
      const int mbase = mwb + mt * 16 + quad * 4;
#pragma unroll
      for (int r = 0; r < 4; ++r)
        C[(size_t)(mbase + r) * DM + n] = acc[mt][nt][r];
    }
}

// ------------------------------------------------------------------- launcher
extern "C" void kernel_launch(void* const* d_in, const int* in_sizes, int n_in,
                              void* d_out, int out_size, void* d_ws, size_t ws_size,
                              hipStream_t stream) {
  const float* x  = (const float*)d_in[0];
  const float* Wq = (const float*)d_in[1];
  const float* Wk = (const float*)d_in[2];
  const float* Wv = (const float*)d_in[3];
  const float* Wo = (const float*)d_in[4];
  float* out = (float*)d_out;

  short* xb  = (short*)d_ws;                       // 8192*768
  short* Wqb = xb  + (size_t)MTOT * DM;
  short* Wkb = Wqb + DM * DM;
  short* Wvb = Wkb + DM * DM;
  short* Wob = Wvb + DM * DM;
  short* Qb  = Wob + DM * DM;                      // (b,h,s,d)
  short* Kb  = Qb  + (size_t)MTOT * DM;            // (b,h,s,d)
  short* VTb = Kb  + (size_t)MTOT * DM;            // (b,h,d,s)
  short* AOb = xb;                                 // alias: xb dead after qkv_gemm

  const int TOT4 = (MTOT * DM + 4 * DM * DM) / 4;
  cvt5_kernel<<<(TOT4 + 255) / 256, 256, 0, stream>>>(x, Wq, Wk, Wv, Wo, xb);

  qkv_gemm<<<dim3(3 * DM / 128, MTOT / 128), 256, 0, stream>>>(xb, Wqb, Qb, Kb, VTb);
  attn_kernel<<<dim3(768), 256, 0, stream>>>(Qb, Kb, VTb, AOb);
  out_gemm<<<dim3(DM / 128, MTOT / 128), 256, 0, stream>>>(AOb, Wob, out);
}

// Round 9
// 217.943 us; speedup vs baseline: 1.1162x; 1.0289x over previous
//
#include <hip/hip_runtime.h>
#include <hip/hip_bf16.h>

// Problem constants
#define SEQ   2048
#define BATCH 4
#define DM    768
#define NH    12
#define HD    64
#define MTOT  (BATCH*SEQ)   // 8192

typedef short bf16x8 __attribute__((ext_vector_type(8)));   // 8 bf16 = 4 VGPRs
typedef float f32x4  __attribute__((ext_vector_type(4)));

static __device__ __forceinline__ short f2bf(float f) {
  union { __hip_bfloat16 h; short s; } u;
  u.h = __float2bfloat16(f);
  return u.s;
}

// async global->LDS, 16 B per lane (global_load_lds_dwordx4)
static __device__ __forceinline__ void async_cp16(const short* g, short* l) {
  __builtin_amdgcn_global_load_lds(
      (const __attribute__((address_space(1))) void*)g,
      (__attribute__((address_space(3))) void*)l, 16, 0, 0);
}

// ------------------------------------------- fused fp32 -> bf16 (x + 4 weights)
__global__ void cvt5_kernel(const float* __restrict__ x, const float* __restrict__ wq,
                            const float* __restrict__ wk, const float* __restrict__ wv,
                            const float* __restrict__ wo, short* __restrict__ dst) {
  const int NX4 = MTOT * DM / 4, NW4 = DM * DM / 4, TOT4 = NX4 + 4 * NW4;
  int i = blockIdx.x * blockDim.x + threadIdx.x;
  if (i >= TOT4) return;
  const float* src; int off;
  if (i < NX4) { src = x; off = i; }
  else {
    int j = i - NX4; int sel = j / NW4; off = j - sel * NW4;
    src = (sel == 0) ? wq : (sel == 1) ? wk : (sel == 2) ? wv : wo;
  }
  float4 v = reinterpret_cast<const float4*>(src)[off];
  short4 o;
  o.x = f2bf(v.x); o.y = f2bf(v.y); o.z = f2bf(v.z); o.w = f2bf(v.w);
  reinterpret_cast<short4*>(dst)[i] = o;
}

// ---------------------------------------------- 128x128 LDS-staged GEMM core, BK=64
// R7-verified VERBATIM. One stage batch -> one sync -> one compute region ->
// one sync; source-side XOR chunk swizzle, reader XORs slot by lq&7.
static __device__ __forceinline__ void gemm_lds_core(
    const short* __restrict__ A, const short* __restrict__ W,
    short* As, short* Bs, int m0, int n0, f32x4 acc[4][4])
{
  const int t = threadIdx.x;
  const int lane = t & 63, w = t >> 6;
  const int quad = lane >> 4, lq = lane & 15;
  const int mw = (w & 1) * 64, nw = (w >> 1) * 64;
  const int r0 = t >> 3;                  // 0..31
  const int cs = (t & 7) ^ (r0 & 7);      // source chunk for this LDS slot
  const short* ga = A + (size_t)(m0 + r0) * DM + cs * 8;
  const short* gb = W + (size_t)(n0 + r0) * DM + cs * 8;
  short* la = As + t * 8;
  short* lb = Bs + t * 8;
  const int xsw = lq & 7;                 // reader-side XOR (= row & 7)

  for (int k0 = 0; k0 < DM; k0 += 64) {
    async_cp16(ga + k0,           la);
    async_cp16(ga + k0 + 32 * DM, la + 2048);
    async_cp16(ga + k0 + 64 * DM, la + 4096);
    async_cp16(ga + k0 + 96 * DM, la + 6144);
    async_cp16(gb + k0,           lb);
    async_cp16(gb + k0 + 32 * DM, lb + 2048);
    async_cp16(gb + k0 + 64 * DM, lb + 4096);
    async_cp16(gb + k0 + 96 * DM, lb + 6144);
    __syncthreads();
#pragma unroll
    for (int hh = 0; hh < 2; ++hh) {      // K sub-chunk 0..32 then 32..64
      bf16x8 af[4], bfr[4];
      const int sl = (hh * 4 + quad) ^ xsw;
#pragma unroll
      for (int i = 0; i < 4; ++i) {
        af[i]  = *(const bf16x8*)(As + (mw + i * 16 + lq) * 64 + sl * 8);
        bfr[i] = *(const bf16x8*)(Bs + (nw + i * 16 + lq) * 64 + sl * 8);
      }
#pragma unroll
      for (int mt = 0; mt < 4; ++mt)
#pragma unroll
        for (int nt = 0; nt < 4; ++nt)
          acc[mt][nt] = __builtin_amdgcn_mfma_f32_16x16x32_bf16(af[mt], bfr[nt], acc[mt][nt], 0, 0, 0);
    }
    __syncthreads();
  }
}

// XCD-aware bijective block swizzle (T1): grid size must be divisible by 8.
static __device__ __forceinline__ int xcd_swz(int wg, int nwg) {
  return (wg & 7) * (nwg >> 3) + (wg >> 3);
}

// --------------------------------------------------------------- fused QKV projection
__global__ __launch_bounds__(256) void qkv_gemm(
    const short* __restrict__ xb, const short* __restrict__ Wall,
    short* __restrict__ Qb, short* __restrict__ Kb, short* __restrict__ VTb)
{
  __shared__ __align__(16) short As[8192], Bs[8192];
  // grid = 18 x 64 = 1152 blocks (divisible by 8) -> bijective swizzle
  const int nwg = gridDim.x * gridDim.y;
  const int wg = xcd_swz(blockIdx.y * gridDim.x + blockIdx.x, nwg);
  const int m0 = (wg / gridDim.x) * 128, n0 = (wg % gridDim.x) * 128;
  f32x4 acc[4][4] = {};
  gemm_lds_core(xb, Wall, As, Bs, m0, n0, acc);

  const int t = threadIdx.x;
  const int lane = t & 63, w = t >> 6;
  const int quad = lane >> 4, lq = lane & 15;
  const int mwb = m0 + (w & 1) * 64, nwb = n0 + (w >> 1) * 64;
#pragma unroll
  for (int mt = 0; mt < 4; ++mt)
#pragma unroll
    for (int nt = 0; nt < 4; ++nt) {
      const int n = nwb + nt * 16 + lq;
      const int z = n / DM, nn = n % DM;
      const int h = nn >> 6, d = nn & 63;
      const int mbase = mwb + mt * 16 + quad * 4;
      const int b = mbase >> 11, s0 = mbase & 2047;
      if (z == 2) {
        short4 v;
        v.x = f2bf(acc[mt][nt][0]); v.y = f2bf(acc[mt][nt][1]);
        v.z = f2bf(acc[mt][nt][2]); v.w = f2bf(acc[mt][nt][3]);
        *(short4*)(VTb + ((size_t)(b * NH + h) * HD + d) * SEQ + s0) = v;
      } else {
        short* dst = (z == 0) ? Qb : Kb;
#pragma unroll
        for (int r = 0; r < 4; ++r)
          dst[((size_t)(b * NH + h) * SEQ + s0 + r) * HD + d] = f2bf(acc[mt][nt][r]);
      }
    }
}

// ------------------------------------------------------------ flash attention
// Math is the R4/R6/R7-verified body VERBATIM, textually inlined via macro
// (NO lambda -- R3/R5's only structural common factor with the NaN failures).
// KVBLK=64: two 32-key sub-tiles share one stage-batch/__syncthreads pair;
// sub-tiles execute in increasing-kb order with unchanged per-tile math ->
// bit-identical output. Halves the barrier/drain count per key.
#define ATTN_TILE(KSB, VSB, KBT)                                               \
  {                                                                            \
    const short* Kc = (KSB);                                                   \
    const short* Vc = (VSB);                                                   \
    const int kbt = (KBT);                                                     \
    const bool act0 = kbt < E0;                                                \
    f32x4 st0[2] = {}, st1[2] = {};                                            \
    __builtin_amdgcn_s_setprio(1);                                             \
    _Pragma("unroll")                                                          \
    for (int t2 = 0; t2 < 2; ++t2) {                                           \
      const int row = 8 * (lq >> 2) + 4 * t2 + (lq & 3);                       \
      const int sl0 = quad ^ rswz;                                             \
      bf16x8 k0 = *(const bf16x8*)(Kc + row * 64 + sl0 * 8);                   \
      bf16x8 k1 = *(const bf16x8*)(Kc + row * 64 + (sl0 ^ 4) * 8);             \
      st1[t2] = __builtin_amdgcn_mfma_f32_16x16x32_bf16(k0, qf1[0], st1[t2], 0, 0, 0); \
      st1[t2] = __builtin_amdgcn_mfma_f32_16x16x32_bf16(k1, qf1[1], st1[t2], 0, 0, 0); \
      if (act0) {                                                              \
        st0[t2] = __builtin_amdgcn_mfma_f32_16x16x32_bf16(k0, qf0[0], st0[t2], 0, 0, 0); \
        st0[t2] = __builtin_amdgcn_mfma_f32_16x16x32_bf16(k1, qf0[1], st0[t2], 0, 0, 0); \
      }                                                                        \
    }                                                                          \
    __builtin_amdgcn_s_setprio(0);                                             \
    bf16x8 vf[4];                                                              \
    _Pragma("unroll")                                                          \
    for (int mt = 0; mt < 4; ++mt)                                             \
      vf[mt] = *(const bf16x8*)(Vc + (mt * 16 + lq) * 32 + quad * 8);          \
    bf16x8 pf1;                                                                \
    {                                                                          \
      float mx;                                                                \
      if (kbt + 31 <= q1b) {                                                   \
        mx = fmaxf(fmaxf(fmaxf(st1[0][0], st1[0][1]), fmaxf(st1[0][2], st1[0][3])), \
                   fmaxf(fmaxf(st1[1][0], st1[1][1]), fmaxf(st1[1][2], st1[1][3]))); \
      } else {                                                                 \
        const int qv = q1b + lq;                                               \
        mx = -3e38f;                                                           \
        _Pragma("unroll")                                                      \
        for (int t2 = 0; t2 < 2; ++t2)                                         \
          _Pragma("unroll")                                                    \
          for (int r = 0; r < 4; ++r) {                                        \
            const int key = kbt + 8 * quad + 4 * t2 + r;                       \
            const float v = (key <= qv) ? st1[t2][r] : -3e38f;                 \
            st1[t2][r] = v;                                                    \
            mx = fmaxf(mx, v);                                                 \
          }                                                                    \
      }                                                                        \
      mx = fmaxf(mx, __shfl_xor(mx, 16));                                      \
      mx = fmaxf(mx, __shfl_xor(mx, 32));                                      \
      const float mn = fmaxf(m1v, mx);                                         \
      const float al = __builtin_amdgcn_exp2f((m1v - mn) * Cc);                \
      m1v = mn;                                                                \
      float rs = 0.0f;                                                         \
      _Pragma("unroll")                                                        \
      for (int t2 = 0; t2 < 2; ++t2)                                           \
        _Pragma("unroll")                                                      \
        for (int r = 0; r < 4; ++r) {                                          \
          const float p = __builtin_amdgcn_exp2f((st1[t2][r] - mn) * Cc);      \
          rs += p;                                                             \
          pf1[t2 * 4 + r] = f2bf(p);                                           \
        }                                                                      \
      rs += __shfl_xor(rs, 16);                                                \
      rs += __shfl_xor(rs, 32);                                                \
      if (!__all(al == 1.0f)) {                                                \
        l1v *= al;                                                             \
        _Pragma("unroll")                                                      \
        for (int mt = 0; mt < 4; ++mt)                                         \
          _Pragma("unroll")                                                    \
          for (int r = 0; r < 4; ++r)                                          \
            o1[mt][r] *= al;                                                   \
      }                                                                        \
      l1v += rs;                                                               \
    }                                                                          \
    bf16x8 pf0;                                                                \
    if (act0) {                                                                \
      float mx;                                                                \
      if (kbt + 31 <= q0b) {                                                   \
        mx = fmaxf(fmaxf(fmaxf(st0[0][0], st0[0][1]), fmaxf(st0[0][2], st0[0][3])), \
                   fmaxf(fmaxf(st0[1][0], st0[1][1]), fmaxf(st0[1][2], st0[1][3]))); \
      } else {                                                                 \
        const int qv = q0b + lq;                                               \
        mx = -3e38f;                                                           \
        _Pragma("unroll")                                                      \
        for (int t2 = 0; t2 < 2; ++t2)                                         \
          _Pragma("unroll")                                                    \
          for (int r = 0; r < 4; ++r) {                                        \
            const int key = kbt + 8 * quad + 4 * t2 + r;                       \
            const float v = (key <= qv) ? st0[t2][r] : -3e38f;                 \
            st0[t2][r] = v;                                                    \
            mx = fmaxf(mx, v);                                                 \
          }                                                                    \
      }                                                                        \
      mx = fmaxf(mx, __shfl_xor(mx, 16));                                      \
      mx = fmaxf(mx, __shfl_xor(mx, 32));                                      \
      const float mn = fmaxf(m0v, mx);                                         \
      const float al = __builtin_amdgcn_exp2f((m0v - mn) * Cc);                \
      m0v = mn;                                                                \
      float rs = 0.0f;                                                         \
      _Pragma("unroll")                                                        \
      for (int t2 = 0; t2 < 2; ++t2)                                           \
        _Pragma("unroll")                                                      \
        for (int r = 0; r < 4; ++r) {                                          \
          const float p = __builtin_amdgcn_exp2f((st0[t2][r] - mn) * Cc);      \
          rs += p;                                                             \
          pf0[t2 * 4 + r] = f2bf(p);                                           \
        }                                                                      \
      rs += __shfl_xor(rs, 16);                                                \
      rs += __shfl_xor(rs, 32);                                                \
      if (!__all(al == 1.0f)) {                                                \
        l0v *= al;                                                             \
        _Pragma("unroll")                                                      \
        for (int mt = 0; mt < 4; ++mt)                                         \
          _Pragma("unroll")                                                    \
          for (int r = 0; r < 4; ++r)                                          \
            o0[mt][r] *= al;                                                   \
      }                                                                        \
      l0v += rs;                                                               \
    }                                                                          \
    __builtin_amdgcn_s_setprio(1);                                             \
    _Pragma("unroll")                                                          \
    for (int mt = 0; mt < 4; ++mt) {                                           \
      o1[mt] = __builtin_amdgcn_mfma_f32_16x16x32_bf16(vf[mt], pf1, o1[mt], 0, 0, 0); \
      if (act0)                                                                \
        o0[mt] = __builtin_amdgcn_mfma_f32_16x16x32_bf16(vf[mt], pf0, o0[mt], 0, 0, 0); \
    }                                                                          \
    __builtin_amdgcn_s_setprio(0);                                             \
  }

__global__ __launch_bounds__(256) void attn_kernel(
    const short* __restrict__ Qb, const short* __restrict__ Kb,
    const short* __restrict__ VTb, short* __restrict__ AOb)
{
  __shared__ __align__(16) short Ks[2 * 2048];   // [sub][keyoff][hd], chunk-swizzled
  __shared__ __align__(16) short Vs[2 * 2048];   // [sub][hd][keyoff]
  const int bp = blockIdx.x;
  const int bh = bp % 48;
  const int g  = bp / 48;              // 0..15
  const int tid = threadIdx.x;
  const int w = tid >> 6, lane = tid & 63;
  const int quad = lane >> 4, lq = lane & 15;
  const int tp = 4 * g + w;            // pair id 0..63
  const int b = bh / NH, h = bh % NH;
  const int q0b = 16 * tp;             // qt0 query base
  const int q1b = 2032 - 16 * tp;      // qt1 query base
  const int E0 = q0b + 16;             // qt0 key range end
  const int E1 = q1b + 16;             // qt1 key range end
  const int Eblk = 2048 - 64 * g;      // block-uniform loop bound (multiple of 64)

  const short* Qh = Qb  + (size_t)bh * SEQ * HD;
  const short* Kh = Kb  + (size_t)bh * SEQ * HD;
  const short* Vh = VTb + (size_t)bh * HD * SEQ;

  // Q fragments (B-operand): lane holds Q[qb+lq][hh*32+quad*8+j]
  bf16x8 qf0[2], qf1[2];
#pragma unroll
  for (int hh = 0; hh < 2; ++hh) {
    qf0[hh] = *(const bf16x8*)(Qh + (size_t)(q0b + lq) * HD + hh * 32 + quad * 8);
    qf1[hh] = *(const bf16x8*)(Qh + (size_t)(q1b + lq) * HD + hh * 32 + quad * 8);
  }

  f32x4 o0[4] = {}, o1[4] = {};        // O^T[hd=mt*16+quad*4+r][q=qb+lq]
  float m0v = -3e38f, m1v = -3e38f;
  float l0v = 0.0f, l1v = 0.0f;        // full per-lane l (round-0 semantics)
  const float Cc = 0.18033688011112042f;  // log2(e)/sqrt(64)

  // ---- K staging, source-swizzled: LDS slot s of row r holds global chunk
  // s^swz(r); LDS dest stays linear (tid*16B, per global_load_lds rule).
  const int srow = tid >> 3, sslot = tid & 7;
  const int sswz = (srow & 3) | (((srow >> 3) & 1) << 2);
  const short* gK = Kh + (size_t)srow * HD + (sslot ^ sswz) * 8;
  const short* gV = Vh + (size_t)(tid >> 2) * SEQ + (tid & 3) * 8;
  short* lK = Ks + tid * 8;            // sub0 dest; sub1 dest is +2048
  short* lV = Vs + tid * 8;

  // reader-side swizzle: rows 8*(lq>>2)+4*t2+(lq&3) all have
  // swz(row) = (lq&3)|(((lq>>2)&1)<<2)
  const int rswz = (lq & 3) | (((lq >> 2) & 1) << 2);

  // Eblk is a multiple of 64: exactly Eblk/64 iterations, no tail.
  for (int kb = 0; kb < Eblk; kb += 64) {
    async_cp16(gK + (size_t)kb * HD,        lK);
    async_cp16(gK + (size_t)(kb + 32) * HD, lK + 2048);
    async_cp16(gV + kb,      lV);
    async_cp16(gV + kb + 32, lV + 2048);
    __syncthreads();
    if (kb < E1)      ATTN_TILE(Ks,        Vs,        kb)
    if (kb + 32 < E1) ATTN_TILE(Ks + 2048, Vs + 2048, kb + 32)
    __syncthreads();
  }

  // ---- epilogue: normalize, store (l already full per lane)
  {
    const float inv = 1.0f / l1v;
    const int q = q1b + lq;
#pragma unroll
    for (int mt = 0; mt < 4; ++mt) {
      short4 v;
      v.x = f2bf(o1[mt][0] * inv);
      v.y = f2bf(o1[mt][1] * inv);
      v.z = f2bf(o1[mt][2] * inv);
      v.w = f2bf(o1[mt][3] * inv);
      *(short4*)(AOb + ((size_t)(b * SEQ + q)) * DM + h * HD + mt * 16 + quad * 4) = v;
    }
  }
  {
    const float inv = 1.0f / l0v;
    const int q = q0b + lq;
#pragma unroll
    for (int mt = 0; mt < 4; ++mt) {
      short4 v;
      v.x = f2bf(o0[mt][0] * inv);
      v.y = f2bf(o0[mt][1] * inv);
      v.z = f2bf(o0[mt][2] * inv);
      v.w = f2bf(o0[mt][3] * inv);
      *(short4*)(AOb + ((size_t)(b * SEQ + q)) * DM + h * HD + mt * 16 + quad * 4) = v;
    }
  }
}

// ----------------------------------------------------------- output projection
__global__ __launch_bounds__(256) void out_gemm(
    const short* __restrict__ AOb, const short* __restrict__ Wob, float* __restrict__ C)
{
  __shared__ __align__(16) short As[8192], Bs[8192];
  // grid = 6 x 64 = 384 blocks (divisible by 8) -> bijective swizzle
  const int nwg = gridDim.x * gridDim.y;
  const int wg = xcd_swz(blockIdx.y * gridDim.x + blockIdx.x, nwg);
  const int m0 = (wg / gridDim.x) * 128, n0 = (wg % gridDim.x) * 128;
  f32x4 acc[4][4] = {};
  gemm_lds_core(AOb, Wob, As, Bs, m0, n0, acc);

  const int t = threadIdx.x;
  const int lane = t & 63, w = t >> 6;
  const int quad = lane >> 4, lq = lane & 15;
  const int mwb = m0 + (w & 1) * 64, nwb = n0 + (w >> 1) * 64;
#pragma unroll
  for (int mt = 0; mt < 4; ++mt)
#pragma unroll
    for (int nt = 0; nt < 4; ++nt) {
      const int n = nwb + nt * 16 + lq;
      const int mbase = mwb + mt * 16 + quad * 4;
#pragma unroll
      for (int r = 0; r < 4; ++r)
        C[(size_t)(mbase + r) * DM + n] = acc[mt][nt][r];
    }
}

// ------------------------------------------------------------------- launcher
extern "C" void kernel_launch(void* const* d_in, const int* in_sizes, int n_in,
                              void* d_out, int out_size, void* d_ws, size_t ws_size,
                              hipStream_t stream) {
  const float* x  = (const float*)d_in[0];
  const float* Wq = (const float*)d_in[1];
  const float* Wk = (const float*)d_in[2];
  const float* Wv = (const float*)d_in[3];
  const float* Wo = (const float*)d_in[4];
  float* out = (float*)d_out;

  short* xb  = (short*)d_ws;                       // 8192*768
  short* Wqb = xb  + (size_t)MTOT * DM;
  short* Wkb = Wqb + DM * DM;
  short* Wvb = Wkb + DM * DM;
  short* Wob = Wvb + DM * DM;
  short* Qb  = Wob + DM * DM;                      // (b,h,s,d)
  short* Kb  = Qb  + (size_t)MTOT * DM;            // (b,h,s,d)
  short* VTb = Kb  + (size_t)MTOT * DM;            // (b,h,d,s)
  short* AOb = xb;                                 // alias: xb dead after qkv_gemm

  const int TOT4 = (MTOT * DM + 4 * DM * DM) / 4;
  cvt5_kernel<<<(TOT4 + 255) / 256, 256, 0, stream>>>(x, Wq, Wk, Wv, Wo, xb);

  qkv_gemm<<<dim3(3 * DM / 128, MTOT / 128), 256, 0, stream>>>(xb, Wqb, Qb, Kb, VTb);
  attn_kernel<<<dim3(768), 256, 0, stream>>>(Qb, Kb, VTb, AOb);
  out_gemm<<<dim3(DM / 128, MTOT / 128), 256, 0, stream>>>(AOb, Wob, out);
}